// Round 9
// baseline (117.001 us; speedup 1.0000x reference)
//
#include <hip/hip_runtime.h>
#include <math.h>

#define L_SEQ 2048
#define H_CH  512
#define N_ST  64

__device__ __forceinline__ float frcp(float x) { return __builtin_amdgcn_rcpf(x); }
// float2-granular LDS pad for fft buffers
#define A2(i) ((i) + ((i) >> 4))
// float4-slot XOR swizzle for conv window: slot s -> s ^ ((s>>3)&1).
// For 8-aligned window bases, 64 lanes at 8-float stride hit bank-groups
// {0,2,4,6,1,3,5,7} per 8 lanes -> conflict-free ds_read_b128 at EVERY slide.
__device__ __forceinline__ int swq(int i) {
    int s = i >> 2;
    s ^= (s >> 3) & 1;
    return (s << 2) | (i & 3);
}

// ---------------------------------------------------------------------------
// Kernel 0: precompute per-(h,n) Cauchy weights into global scratch.
// ---------------------------------------------------------------------------
__global__ __launch_bounds__(256)
void s4_prep(const float* __restrict__ lam_r_g, const float* __restrict__ lam_i_g,
             const float* __restrict__ p_r_g,  const float* __restrict__ p_i_g,
             const float* __restrict__ b_r_g,  const float* __restrict__ b_i_g,
             const float* __restrict__ c_g,
             float4* __restrict__ Wa, float4* __restrict__ Wb, float* __restrict__ Wc)
{
    const int g = blockIdx.x * 256 + threadIdx.x;      // [0, 512*64)
    const float lr = fminf(lam_r_g[g], -0.0001f);
    const float li = lam_i_g[g];
    const float pr = p_r_g[g], pi = p_i_g[g];
    const float br = b_r_g[g], bi = b_i_g[g];
    const float c0 = c_g[2 * g], c1 = c_g[2 * g + 1];
    Wa[g] = make_float4(lr, li, c0 * br + c1 * bi, c0 * bi - c1 * br);
    Wb[g] = make_float4(c0 * pr + c1 * pi, c0 * pi - c1 * pr,
                        pr * br + pi * bi, pr * bi - pi * br);
    Wc[g] = pr * pr + pi * pi;
}

// ---------------------------------------------------------------------------
// Kernel 1: Cauchy generating function -> roots[h][l] (complex)
// ---------------------------------------------------------------------------
__global__ __launch_bounds__(256)
void s4_cauchy(const float4* __restrict__ Wa, const float4* __restrict__ Wb,
               const float* __restrict__ Wc, const float* __restrict__ log_step_g,
               float2* __restrict__ roots)
{
    const int h = blockIdx.y;
    const int l = blockIdx.x * 256 + threadIdx.x;

    const float step = expf(log_step_g[h]);
    const float ts   = 2.0f / step;

    const float ang = -6.2831853071795864769f * ((float)l * (1.0f / (float)L_SEQ));
    float wi, wr;
    sincosf(ang, &wi, &wr);                      // omega = (wr, wi)

    const float dr = 1.0f + wr, di = wi;         // 1 + omega
    const float dinv = frcp(dr * dr + di * di);
    const float nr = 1.0f - wr, ni = -wi;        // 1 - omega
    const float gr = ts * (nr * dr + ni * di) * dinv;
    const float gi = ts * (ni * dr - nr * di) * dinv;
    const float c2r = 2.0f * dr * dinv;
    const float c2i = -2.0f * di * dinv;

    const float4* __restrict__ wa = Wa + h * N_ST;
    const float4* __restrict__ wb = Wb + h * N_ST;
    const float*  __restrict__ wc = Wc + h * N_ST;

    float k00r = 0.f, k00i = 0.f, k01r = 0.f, k01i = 0.f;
    float k10r = 0.f, k10i = 0.f, k11r = 0.f, k11i = 0.f;
#pragma unroll 4
    for (int n = 0; n < N_ST; ++n) {
        const float4 A = wa[n];
        const float4 B = wb[n];
        const float w11 = wc[n];
        const float ddr = gr - A.x;
        const float ddi = gi - A.y;
        const float rinv = frcp(fmaf(ddr, ddr, ddi * ddi));
        const float rr = ddr * rinv;
        const float ri = -ddi * rinv;
        k00r = fmaf(A.z, rr, fmaf(-A.w, ri, k00r));
        k00i = fmaf(A.z, ri, fmaf( A.w, rr, k00i));
        k01r = fmaf(B.x, rr, fmaf(-B.y, ri, k01r));
        k01i = fmaf(B.x, ri, fmaf( B.y, rr, k01i));
        k10r = fmaf(B.z, rr, fmaf(-B.w, ri, k10r));
        k10i = fmaf(B.z, ri, fmaf( B.w, rr, k10i));
        k11r = fmaf(w11, rr, k11r);
        k11i = fmaf(w11, ri, k11i);
    }

    const float qdr = 1.0f + k11r, qdi = k11i;
    const float qinv = frcp(qdr * qdr + qdi * qdi);
    const float pnr = k01r * k10r - k01i * k10i;
    const float pni = k01r * k10i + k01i * k10r;
    const float qr = (pnr * qdr + pni * qdi) * qinv;
    const float qi = (pni * qdr - pnr * qdi) * qinv;
    const float rr0 = k00r - qr;
    const float ri0 = k00i - qi;
    roots[h * L_SEQ + l] = make_float2(c2r * rr0 - c2i * ri0,
                                       c2r * ri0 + c2i * rr0);
}

// ---------------------------------------------------------------------------
// Kernel 2: kern[h] = Re(ifft_2048(roots[h])) via half-size complex iFFT (R7).
// ---------------------------------------------------------------------------
__global__ __launch_bounds__(256)
void s4_ifft(const float2* __restrict__ roots, float2* __restrict__ kern2)
{
    __shared__ float2 buf[1088];   // A2(1023)=1086
    __shared__ float2 tw[544];     // A2(511)=542, tw[k]=e^{+2pi i k/1024}
    const int h   = blockIdx.x;
    const int tid = threadIdx.x;
    const float2* __restrict__ r = roots + h * L_SEQ;

    for (int k = tid; k < 512; k += 256) {
        float sv, cv;
        sincosf((float)k * (6.2831853071795864769f / 1024.0f), &sv, &cv);
        tw[A2(k)] = make_float2(cv, sv);
    }

#pragma unroll
    for (int q = 0; q < 4; ++q) {
        const int k = tid + q * 256;
        float zr, zi;
        if (k == 0) {
            const float X0 = r[0].x, XM = r[1024].x;
            zr = X0 + XM;  zi = X0 - XM;
        } else {
            const float2 a  = r[k],        b2 = r[2048 - k];
            const float2 a2 = r[1024 - k], b3 = r[1024 + k];
            const float xkr = 0.5f * (a.x + b2.x),  xki = 0.5f * (a.y - b2.y);
            const float xmr = 0.5f * (a2.x + b3.x), xmi = -0.5f * (a2.y - b3.y);
            const float er = xkr + xmr, ei = xki + xmi;
            const float o_r = xkr - xmr, o_i = xki - xmi;
            float sv, cv;
            sincosf((float)k * (6.2831853071795864769f / 2048.0f), &sv, &cv);
            zr = er - fmaf(cv, o_i,  sv * o_r);
            zi = ei + fmaf(cv, o_r, -sv * o_i);
        }
        buf[A2(k)] = make_float2(zr, zi);
    }
    __syncthreads();

#pragma unroll
    for (int st = 0; st < 10; ++st) {
        const int h2s = 512 >> st;              // half butterfly span
#pragma unroll
        for (int bq = 0; bq < 2; ++bq) {
            const int b  = tid + bq * 256;      // butterfly id [0,512)
            const int j  = b & (h2s - 1);
            const int i0 = ((b >> (9 - st)) << (10 - st)) + j;
            const int i1 = i0 + h2s;
            const float2 u = buf[A2(i0)];
            const float2 v = buf[A2(i1)];
            const float2 w = tw[A2(j << st)];   // e^{+2pi i j/len}
            buf[A2(i0)] = make_float2(u.x + v.x, u.y + v.y);
            const float d0 = u.x - v.x, d1 = u.y - v.y;
            buf[A2(i1)] = make_float2(d0 * w.x - d1 * w.y, d0 * w.y + d1 * w.x);
        }
        __syncthreads();
    }

#pragma unroll
    for (int q = 0; q < 4; ++q) {
        const int n  = tid + q * 256;
        const int br = __brev(n) >> 22;         // 10-bit reversal
        const float2 z = buf[A2(br)];
        kern2[h * 1024 + n] = make_float2(z.x * (1.0f / 2048.0f),
                                          z.y * (1.0f / 2048.0f));
    }
}

// ---------------------------------------------------------------------------
// Kernel 3: causal conv, 3 identical-shape block classes per h.
// 2-pair A/B window rotation (copy-free), conflict-free swq LDS layout,
// launch_bounds(128,2) to release the VGPR cap. Outputs written RAW and
// COALESCED in [h][t] layout (CA for cls0/cls1 halves, CB for cls2);
// transpose + d*u add happens in s4_finish.
// ---------------------------------------------------------------------------
#define CONV8(L0,L1,H0,H1,TAPS) do {                                          \
    const float4 ka = *(const float4*)(kr + (TAPS));                          \
    const float4 kb = *(const float4*)(kr + (TAPS) + 4);                      \
    ac0=fmaf(ka.x,L1.w,ac0); ac0=fmaf(ka.y,L1.z,ac0); ac0=fmaf(ka.z,L1.y,ac0); ac0=fmaf(ka.w,L1.x,ac0); \
    ac0=fmaf(kb.x,L0.w,ac0); ac0=fmaf(kb.y,L0.z,ac0); ac0=fmaf(kb.z,L0.y,ac0); ac0=fmaf(kb.w,L0.x,ac0); \
    ac1=fmaf(ka.x,H0.x,ac1); ac1=fmaf(ka.y,L1.w,ac1); ac1=fmaf(ka.z,L1.z,ac1); ac1=fmaf(ka.w,L1.y,ac1); \
    ac1=fmaf(kb.x,L1.x,ac1); ac1=fmaf(kb.y,L0.w,ac1); ac1=fmaf(kb.z,L0.z,ac1); ac1=fmaf(kb.w,L0.y,ac1); \
    ac2=fmaf(ka.x,H0.y,ac2); ac2=fmaf(ka.y,H0.x,ac2); ac2=fmaf(ka.z,L1.w,ac2); ac2=fmaf(ka.w,L1.z,ac2); \
    ac2=fmaf(kb.x,L1.y,ac2); ac2=fmaf(kb.y,L1.x,ac2); ac2=fmaf(kb.z,L0.w,ac2); ac2=fmaf(kb.w,L0.z,ac2); \
    ac3=fmaf(ka.x,H0.z,ac3); ac3=fmaf(ka.y,H0.y,ac3); ac3=fmaf(ka.z,H0.x,ac3); ac3=fmaf(ka.w,L1.w,ac3); \
    ac3=fmaf(kb.x,L1.z,ac3); ac3=fmaf(kb.y,L1.y,ac3); ac3=fmaf(kb.z,L1.x,ac3); ac3=fmaf(kb.w,L0.w,ac3); \
    ac4=fmaf(ka.x,H0.w,ac4); ac4=fmaf(ka.y,H0.z,ac4); ac4=fmaf(ka.z,H0.y,ac4); ac4=fmaf(ka.w,H0.x,ac4); \
    ac4=fmaf(kb.x,L1.w,ac4); ac4=fmaf(kb.y,L1.z,ac4); ac4=fmaf(kb.z,L1.y,ac4); ac4=fmaf(kb.w,L1.x,ac4); \
    ac5=fmaf(ka.x,H1.x,ac5); ac5=fmaf(ka.y,H0.w,ac5); ac5=fmaf(ka.z,H0.z,ac5); ac5=fmaf(ka.w,H0.y,ac5); \
    ac5=fmaf(kb.x,H0.x,ac5); ac5=fmaf(kb.y,L1.w,ac5); ac5=fmaf(kb.z,L1.z,ac5); ac5=fmaf(kb.w,L1.y,ac5); \
    ac6=fmaf(ka.x,H1.y,ac6); ac6=fmaf(ka.y,H1.x,ac6); ac6=fmaf(ka.z,H0.w,ac6); ac6=fmaf(ka.w,H0.z,ac6); \
    ac6=fmaf(kb.x,H0.y,ac6); ac6=fmaf(kb.y,H0.x,ac6); ac6=fmaf(kb.z,L1.w,ac6); ac6=fmaf(kb.w,L1.z,ac6); \
    ac7=fmaf(ka.x,H1.z,ac7); ac7=fmaf(ka.y,H1.y,ac7); ac7=fmaf(ka.z,H1.x,ac7); ac7=fmaf(ka.w,H0.w,ac7); \
    ac7=fmaf(kb.x,H0.z,ac7); ac7=fmaf(kb.y,H0.y,ac7); ac7=fmaf(kb.z,H0.x,ac7); ac7=fmaf(kb.w,L1.w,ac7); \
} while (0)

#define LDPAIR(P0,P1,IDX) do {                                                \
    P0 = *(const float4*)(su + swq(IDX));                                     \
    P1 = *(const float4*)(su + swq((IDX) + 4)); } while (0)

__global__ __launch_bounds__(128, 2)
void s4_conv(const float* __restrict__ kern, const float* __restrict__ u,
             float* __restrict__ CA, float* __restrict__ CB)
{
    __shared__ __align__(16) float su[2064];
    const int cls = blockIdx.x;                // 0,1,2
    const int h   = blockIdx.y;
    const int tid = threadIdx.x;               // [0,128)
    const int tl  = tid * 8;                   // local output base

    for (int i = tid; i < 2064; i += 128) su[i] = 0.0f;  // swq is bijective
    __syncthreads();
    if (cls == 1) {
        for (int j = tid; j < 2048; j += 128) su[swq(7 + j)] = u[j * H_CH + h];
    } else {
        for (int j = tid; j < 1024; j += 128) su[swq(1031 + j)] = u[j * H_CH + h];
    }
    __syncthreads();

    const float* __restrict__ kr = kern + h * L_SEQ + (cls == 2 ? 1024 : 0);

    float ac0 = 0.f, ac1 = 0.f, ac2 = 0.f, ac3 = 0.f;
    float ac4 = 0.f, ac5 = 0.f, ac6 = 0.f, ac7 = 0.f;

    float4 A0, A1, B0, B1;
    int W = tl + 1024;                         // window base (logical su index)
    LDPAIR(B0, B1, W + 8);                     // hi pair for first chunk

    for (int it = 0; it < 32; ++it) {
        const int s0 = it << 5;
        LDPAIR(A0, A1, W);       CONV8(A0, A1, B0, B1, s0);
        LDPAIR(B0, B1, W - 8);   CONV8(B0, B1, A0, A1, s0 + 8);
        LDPAIR(A0, A1, W - 16);  CONV8(A0, A1, B0, B1, s0 + 16);
        LDPAIR(B0, B1, W - 24);  CONV8(B0, B1, A0, A1, s0 + 24);
        W -= 32;
    }

    float* __restrict__ dst = (cls == 0) ? (CA + h * 2048 + tl)
                            : (cls == 1) ? (CA + h * 2048 + 1024 + tl)
                                         : (CB + h * 1024 + tl);
    *(float4*)(dst)     = make_float4(ac0, ac1, ac2, ac3);
    *(float4*)(dst + 4) = make_float4(ac4, ac5, ac6, ac7);
}

// ---------------------------------------------------------------------------
// Kernel 4: finish = 64x64 LDS transpose of conv results + d*u add.
// out[t][h] = CA[h][t] (+ CB[h][t-1024] for t>=1024) + d[h]*u[t][h]
// ---------------------------------------------------------------------------
__global__ __launch_bounds__(256)
void s4_finish(const float* __restrict__ CA, const float* __restrict__ CB,
               const float* __restrict__ u, const float* __restrict__ dvec,
               float* __restrict__ out)
{
    __shared__ float tile[64][65];
    const int t0   = blockIdx.x * 64;
    const int h0   = blockIdx.y * 64;
    const int lane = threadIdx.x & 63;
    const int rowg = threadIdx.x >> 6;         // 0..3
    const bool upper = (t0 >= 1024);

#pragma unroll
    for (int rr = 0; rr < 16; ++rr) {
        const int hr = rowg * 16 + rr;
        float v = CA[(h0 + hr) * 2048 + t0 + lane];
        if (upper) v += CB[(h0 + hr) * 1024 + (t0 - 1024) + lane];
        tile[hr][lane] = v;
    }
    __syncthreads();

    const float dh = dvec[h0 + lane];
#pragma unroll
    for (int rr = 0; rr < 16; ++rr) {
        const int tr = rowg * 16 + rr;
        const int t  = t0 + tr;
        out[t * H_CH + h0 + lane] =
            fmaf(dh, u[t * H_CH + h0 + lane], tile[lane][tr]);
    }
}

// ---------------------------------------------------------------------------
extern "C" void kernel_launch(void* const* d_in, const int* in_sizes, int n_in,
                              void* d_out, int out_size, void* d_ws, size_t ws_size,
                              hipStream_t stream)
{
    const float* u        = (const float*)d_in[0];
    const float* lam_r    = (const float*)d_in[1];
    const float* lam_i    = (const float*)d_in[2];
    const float* p_r      = (const float*)d_in[3];
    const float* p_i      = (const float*)d_in[4];
    const float* b_r      = (const float*)d_in[5];
    const float* b_i      = (const float*)d_in[6];
    const float* cmat     = (const float*)d_in[7];
    const float* dvec     = (const float*)d_in[8];
    const float* log_step = (const float*)d_in[9];
    float* out = (float*)d_out;

    char* ws = (char*)d_ws;
    float2* roots = (float2*)ws;                              // 8 MB @ 0 (dead after ifft)
    float*  kern  = (float*)(ws + (size_t)8 * 1024 * 1024);   // 4 MB @ 8M
    float*  CA    = (float*)ws;                               // 4 MB @ 0  (over dead roots)
    float*  CB    = (float*)(ws + (size_t)4 * 1024 * 1024);   // 2 MB @ 4M (over dead roots)
    float4* Wa    = (float4*)(ws + (size_t)12 * 1024 * 1024); // 512 KB
    float4* Wb    = (float4*)(ws + (size_t)12 * 1024 * 1024 + 512 * 1024);
    float*  Wc    = (float*) (ws + (size_t)13 * 1024 * 1024); // 128 KB

    s4_prep<<<dim3(H_CH * N_ST / 256), dim3(256), 0, stream>>>(
        lam_r, lam_i, p_r, p_i, b_r, b_i, cmat, Wa, Wb, Wc);
    s4_cauchy<<<dim3(L_SEQ / 256, H_CH), dim3(256), 0, stream>>>(
        Wa, Wb, Wc, log_step, roots);
    s4_ifft<<<dim3(H_CH), dim3(256), 0, stream>>>(roots, (float2*)kern);
    s4_conv<<<dim3(3, H_CH), dim3(128), 0, stream>>>(kern, u, CA, CB);
    s4_finish<<<dim3(L_SEQ / 64, H_CH / 64), dim3(256), 0, stream>>>(
        CA, CB, u, dvec, out);
}

// Round 10
// 78.450 us; speedup vs baseline: 1.4914x; 1.4914x over previous
//
#include <hip/hip_runtime.h>
#include <math.h>

#define L_SEQ 2048
#define H_CH  512
#define N_ST  64

__device__ __forceinline__ float frcp(float x) { return __builtin_amdgcn_rcpf(x); }
// float2-granular LDS pad for FFT buffers
#define A2(i) ((i) + ((i) >> 4))

// ---------------------------------------------------------------------------
// Shared radix-2 DIF FFT in LDS. Natural-order input, bit-reversed output.
// Table tw[A2(k)] = e^{+2pi i k/2048}, k<1024. ssign=-1 -> forward (e^-),
// ssign=+1 -> inverse (e^+, unnormalized). Works for N=1024/2048 via LOGN.
// ---------------------------------------------------------------------------
template<int LOGN>
__device__ __forceinline__ void fft_lds(float2* buf, const float2* tw,
                                        int tid, float ssign)
{
    constexpr int N   = 1 << LOGN;
    constexpr int NBF = N / 512;                 // butterflies/thread/stage
#pragma unroll
    for (int st = 0; st < LOGN; ++st) {
        const int h2s = (N >> 1) >> st;
#pragma unroll
        for (int bq = 0; bq < NBF; ++bq) {
            const int b  = tid + bq * 256;
            const int j  = b & (h2s - 1);
            const int i0 = ((b >> (LOGN - 1 - st)) << (LOGN - st)) + j;
            const int i1 = i0 + h2s;
            const float2 uu = buf[A2(i0)];
            const float2 vv = buf[A2(i1)];
            const float2 w  = tw[A2((j << st) << (11 - LOGN))];
            const float  wy = ssign * w.y;
            buf[A2(i0)] = make_float2(uu.x + vv.x, uu.y + vv.y);
            const float d0 = uu.x - vv.x, d1 = uu.y - vv.y;
            buf[A2(i1)] = make_float2(d0 * w.x - d1 * wy, d0 * wy + d1 * w.x);
        }
        __syncthreads();
    }
}

// ---------------------------------------------------------------------------
// Kernel 0: precompute per-(h,n) Cauchy weights into global scratch.
// ---------------------------------------------------------------------------
__global__ __launch_bounds__(256)
void s4_prep(const float* __restrict__ lam_r_g, const float* __restrict__ lam_i_g,
             const float* __restrict__ p_r_g,  const float* __restrict__ p_i_g,
             const float* __restrict__ b_r_g,  const float* __restrict__ b_i_g,
             const float* __restrict__ c_g,
             float4* __restrict__ Wa, float4* __restrict__ Wb, float* __restrict__ Wc)
{
    const int g = blockIdx.x * 256 + threadIdx.x;      // [0, 512*64)
    const float lr = fminf(lam_r_g[g], -0.0001f);
    const float li = lam_i_g[g];
    const float pr = p_r_g[g], pi = p_i_g[g];
    const float br = b_r_g[g], bi = b_i_g[g];
    const float c0 = c_g[2 * g], c1 = c_g[2 * g + 1];
    Wa[g] = make_float4(lr, li, c0 * br + c1 * bi, c0 * bi - c1 * br);
    Wb[g] = make_float4(c0 * pr + c1 * pi, c0 * pi - c1 * pr,
                        pr * br + pi * bi, pr * bi - pi * br);
    Wc[g] = pr * pr + pi * pi;
}

// ---------------------------------------------------------------------------
// Kernel 1: Cauchy generating function -> roots[h][l] (complex)
// ---------------------------------------------------------------------------
__global__ __launch_bounds__(256)
void s4_cauchy(const float4* __restrict__ Wa, const float4* __restrict__ Wb,
               const float* __restrict__ Wc, const float* __restrict__ log_step_g,
               float2* __restrict__ roots)
{
    const int h = blockIdx.y;
    const int l = blockIdx.x * 256 + threadIdx.x;

    const float step = expf(log_step_g[h]);
    const float ts   = 2.0f / step;

    const float ang = -6.2831853071795864769f * ((float)l * (1.0f / (float)L_SEQ));
    float wi, wr;
    sincosf(ang, &wi, &wr);                      // omega = (wr, wi)

    const float dr = 1.0f + wr, di = wi;         // 1 + omega
    const float dinv = frcp(dr * dr + di * di);
    const float nr = 1.0f - wr, ni = -wi;        // 1 - omega
    const float gr = ts * (nr * dr + ni * di) * dinv;
    const float gi = ts * (ni * dr - nr * di) * dinv;
    const float c2r = 2.0f * dr * dinv;
    const float c2i = -2.0f * di * dinv;

    const float4* __restrict__ wa = Wa + h * N_ST;
    const float4* __restrict__ wb = Wb + h * N_ST;
    const float*  __restrict__ wc = Wc + h * N_ST;

    float k00r = 0.f, k00i = 0.f, k01r = 0.f, k01i = 0.f;
    float k10r = 0.f, k10i = 0.f, k11r = 0.f, k11i = 0.f;
#pragma unroll 4
    for (int n = 0; n < N_ST; ++n) {
        const float4 A = wa[n];
        const float4 B = wb[n];
        const float w11 = wc[n];
        const float ddr = gr - A.x;
        const float ddi = gi - A.y;
        const float rinv = frcp(fmaf(ddr, ddr, ddi * ddi));
        const float rr = ddr * rinv;
        const float ri = -ddi * rinv;
        k00r = fmaf(A.z, rr, fmaf(-A.w, ri, k00r));
        k00i = fmaf(A.z, ri, fmaf( A.w, rr, k00i));
        k01r = fmaf(B.x, rr, fmaf(-B.y, ri, k01r));
        k01i = fmaf(B.x, ri, fmaf( B.y, rr, k01i));
        k10r = fmaf(B.z, rr, fmaf(-B.w, ri, k10r));
        k10i = fmaf(B.z, ri, fmaf( B.w, rr, k10i));
        k11r = fmaf(w11, rr, k11r);
        k11i = fmaf(w11, ri, k11i);
    }

    const float qdr = 1.0f + k11r, qdi = k11i;
    const float qinv = frcp(qdr * qdr + qdi * qdi);
    const float pnr = k01r * k10r - k01i * k10i;
    const float pni = k01r * k10i + k01i * k10r;
    const float qr = (pnr * qdr + pni * qdi) * qinv;
    const float qi = (pni * qdr - pnr * qdi) * qinv;
    const float rr0 = k00r - qr;
    const float ri0 = k00i - qi;
    roots[h * L_SEQ + l] = make_float2(c2r * rr0 - c2i * ri0,
                                       c2r * ri0 + c2i * rr0);
}

// ---------------------------------------------------------------------------
// Kernel 2: fused spectral convolution, one block per h.
//  phase 1 (R7-proven): roots -> kern via half-size irfft (1024-pt iFFT)
//  phase 2: Zk = fft2048(k0 + i*k1, zero-padded)     [forward]
//  phase 3: Zu = fft2048(u0 + i*u1, zero-padded)     [forward]
//  phase 4: unpack Hermitian pairs, R = F0*U0 + i(F0*U1 + F1*U0)
//  phase 5: r = ifft2048(R)/2048; out_lo = Re r[t]; out_hi = Re r[t+1024]+Im r[t]
//  (k0*u0 len 2047 < 2048 -> exact linear conv; k1*u1 falls beyond L, dropped)
// Writes Y[h][t] (coalesced); transpose + d*u in s4_finish.
// ---------------------------------------------------------------------------
__global__ __launch_bounds__(256)
void s4_fftconv(const float2* __restrict__ roots, const float* __restrict__ u,
                float* __restrict__ Y)
{
    __shared__ float2 bufK[2175];   // A2(2047)=2174
    __shared__ float2 bufU[2175];
    __shared__ float2 tw[1087];     // A2(1023)=1086
    const int h   = blockIdx.x;
    const int tid = threadIdx.x;
    const float2* __restrict__ r = roots + h * L_SEQ;

    // prefetch u column early (global, strided; consumed in phase 3)
    float uv[8];
#pragma unroll
    for (int q = 0; q < 4; ++q) {
        const int t = tid + q * 256;
        uv[q]     = u[t * H_CH + h];
        uv[q + 4] = u[(t + 1024) * H_CH + h];
    }

    for (int k = tid; k < 1024; k += 256) {
        float sv, cv;
        sincosf((float)k * (6.2831853071795864769f / 2048.0f), &sv, &cv);
        tw[A2(k)] = make_float2(cv, sv);
    }

    // ---- phase 1 prologue: half-size irfft pack (verbatim R7) ----
#pragma unroll
    for (int q = 0; q < 4; ++q) {
        const int k = tid + q * 256;
        float zr, zi;
        if (k == 0) {
            const float X0 = r[0].x, XM = r[1024].x;
            zr = X0 + XM;  zi = X0 - XM;
        } else {
            const float2 a  = r[k],        b2 = r[2048 - k];
            const float2 a2 = r[1024 - k], b3 = r[1024 + k];
            const float xkr = 0.5f * (a.x + b2.x),  xki = 0.5f * (a.y - b2.y);
            const float xmr = 0.5f * (a2.x + b3.x), xmi = -0.5f * (a2.y - b3.y);
            const float er = xkr + xmr, ei = xki + xmi;
            const float o_r = xkr - xmr, o_i = xki - xmi;
            float sv, cv;
            sincosf((float)k * (6.2831853071795864769f / 2048.0f), &sv, &cv);
            zr = er - fmaf(cv, o_i,  sv * o_r);
            zi = ei + fmaf(cv, o_r, -sv * o_i);
        }
        bufK[A2(k)] = make_float2(zr, zi);
    }
    __syncthreads();
    fft_lds<10>(bufK, tw, tid, 1.0f);      // z[n] at bufK[A2(brev10(n))]

    // ---- phase 2: build v = k0 + i*k1 (scaled 1/2048), pad, forward FFT ----
    float2 v0[4];
#pragma unroll
    for (int q = 0; q < 4; ++q) {
        const int t  = tid + q * 256;      // t in [0,1024)
        const int n0 = t >> 1;             // kern[t]      = z[n0].(t&1)
        const float2 za = bufK[A2(__brev(n0) >> 22)];
        const float2 zb = bufK[A2(__brev(512 + n0) >> 22)];   // kern[1024+t]
        const float k0v = ((t & 1) ? za.y : za.x) * (1.0f / 2048.0f);
        const float k1v = ((t & 1) ? zb.y : zb.x) * (1.0f / 2048.0f);
        v0[q] = make_float2(k0v, k1v);
    }
    __syncthreads();
#pragma unroll
    for (int q = 0; q < 4; ++q) {
        const int t = tid + q * 256;
        bufK[A2(t)]        = v0[q];
        bufK[A2(t + 1024)] = make_float2(0.f, 0.f);
    }
    __syncthreads();
    fft_lds<11>(bufK, tw, tid, -1.0f);     // Zk, bit-rev(11)

    // ---- phase 3: u pack, forward FFT ----
#pragma unroll
    for (int q = 0; q < 4; ++q) {
        const int t = tid + q * 256;
        bufU[A2(t)]        = make_float2(uv[q], uv[q + 4]);
        bufU[A2(t + 1024)] = make_float2(0.f, 0.f);
    }
    __syncthreads();
    fft_lds<11>(bufU, tw, tid, -1.0f);     // Zu, bit-rev(11)

    // ---- phase 4: Hermitian unpack + pointwise product (into regs) ----
    float2 R[8];
#pragma unroll
    for (int q = 0; q < 8; ++q) {
        const int m  = tid + q * 256;
        const int mp = (2048 - m) & 2047;
        const int bm = __brev(m)  >> 21;
        const int bp = __brev(mp) >> 21;
        const float2 Zk  = bufK[A2(bm)], Zkp = bufK[A2(bp)];
        const float2 Zu  = bufU[A2(bm)], Zup = bufU[A2(bp)];
        const float F0r = 0.5f * (Zk.x + Zkp.x), F0i = 0.5f * (Zk.y - Zkp.y);
        const float F1r = 0.5f * (Zk.y + Zkp.y), F1i = 0.5f * (Zkp.x - Zk.x);
        const float U0r = 0.5f * (Zu.x + Zup.x), U0i = 0.5f * (Zu.y - Zup.y);
        const float U1r = 0.5f * (Zu.y + Zup.y), U1i = 0.5f * (Zup.x - Zu.x);
        const float Pr = F0r * U0r - F0i * U0i;
        const float Pi = F0r * U0i + F0i * U0r;
        const float Qr = F0r * U1r - F0i * U1i + F1r * U0r - F1i * U0i;
        const float Qi = F0r * U1i + F0i * U1r + F1r * U0i + F1i * U0r;
        R[q] = make_float2(Pr - Qi, Pi + Qr);          // R = P + iQ
    }
    __syncthreads();
#pragma unroll
    for (int q = 0; q < 8; ++q) bufK[A2(tid + q * 256)] = R[q];
    __syncthreads();
    fft_lds<11>(bufK, tw, tid, 1.0f);      // r (unnormalized), bit-rev(11)

    // ---- phase 5: epilogue ----
#pragma unroll
    for (int q = 0; q < 4; ++q) {
        const int t = tid + q * 256;       // t in [0,1024)
        const float2 rl = bufK[A2(__brev(t)        >> 21)];
        const float2 rh = bufK[A2(__brev(t + 1024) >> 21)];
        Y[h * 2048 + t]        = rl.x * (1.0f / 2048.0f);
        Y[h * 2048 + 1024 + t] = (rh.x + rl.y) * (1.0f / 2048.0f);
    }
}

// ---------------------------------------------------------------------------
// Kernel 3: finish = 64x64 LDS transpose + d*u add.
// out[t][h] = Y[h][t] + d[h]*u[t][h]
// ---------------------------------------------------------------------------
__global__ __launch_bounds__(256)
void s4_finish(const float* __restrict__ Y, const float* __restrict__ u,
               const float* __restrict__ dvec, float* __restrict__ out)
{
    __shared__ float tile[64][65];
    const int t0   = blockIdx.x * 64;
    const int h0   = blockIdx.y * 64;
    const int lane = threadIdx.x & 63;
    const int rowg = threadIdx.x >> 6;         // 0..3

#pragma unroll
    for (int rr = 0; rr < 16; ++rr) {
        const int hr = rowg * 16 + rr;
        tile[hr][lane] = Y[(h0 + hr) * 2048 + t0 + lane];
    }
    __syncthreads();

    const float dh = dvec[h0 + lane];
#pragma unroll
    for (int rr = 0; rr < 16; ++rr) {
        const int tr = rowg * 16 + rr;
        const int t  = t0 + tr;
        out[t * H_CH + h0 + lane] =
            fmaf(dh, u[t * H_CH + h0 + lane], tile[lane][tr]);
    }
}

// ---------------------------------------------------------------------------
extern "C" void kernel_launch(void* const* d_in, const int* in_sizes, int n_in,
                              void* d_out, int out_size, void* d_ws, size_t ws_size,
                              hipStream_t stream)
{
    const float* u        = (const float*)d_in[0];
    const float* lam_r    = (const float*)d_in[1];
    const float* lam_i    = (const float*)d_in[2];
    const float* p_r      = (const float*)d_in[3];
    const float* p_i      = (const float*)d_in[4];
    const float* b_r      = (const float*)d_in[5];
    const float* b_i      = (const float*)d_in[6];
    const float* cmat     = (const float*)d_in[7];
    const float* dvec     = (const float*)d_in[8];
    const float* log_step = (const float*)d_in[9];
    float* out = (float*)d_out;

    char* ws = (char*)d_ws;
    float2* roots = (float2*)ws;                              // 8 MB @ 0
    float*  Y     = (float*)(ws + (size_t)8 * 1024 * 1024);   // 4 MB @ 8M
    float4* Wa    = (float4*)(ws + (size_t)12 * 1024 * 1024); // 512 KB
    float4* Wb    = (float4*)(ws + (size_t)12 * 1024 * 1024 + 512 * 1024);
    float*  Wc    = (float*) (ws + (size_t)13 * 1024 * 1024); // 128 KB

    s4_prep<<<dim3(H_CH * N_ST / 256), dim3(256), 0, stream>>>(
        lam_r, lam_i, p_r, p_i, b_r, b_i, cmat, Wa, Wb, Wc);
    s4_cauchy<<<dim3(L_SEQ / 256, H_CH), dim3(256), 0, stream>>>(
        Wa, Wb, Wc, log_step, roots);
    s4_fftconv<<<dim3(H_CH), dim3(256), 0, stream>>>(roots, u, Y);
    s4_finish<<<dim3(L_SEQ / 64, H_CH / 64), dim3(256), 0, stream>>>(
        Y, u, dvec, out);
}